// Round 7
// baseline (71.429 us; speedup 1.0000x reference)
//
#include <hip/hip_runtime.h>

#define BD 4
#define CD 3
#define HD 512
#define WD 512
#define NPAT 4096
#define NP (BD * NPAT)            // 16384 patches
#define PLANE (HD * WD)
#define PPW 4                     // patches per wave (16 lanes each, 1 row/lane)
#define PPB 16                    // patches per 256-thread block
#define NBLK (NP / PPB)           // 1024 stage1 blocks
#define TOTAL_ELEMS (4.0 * 3.0 * 4096.0 * 256.0)   // 12,582,912

typedef float f4 __attribute__((ext_vector_type(4), aligned(4)));

// ---- kernel 1: per-batch counting sort by 32-row h-band; packs (b,h,w) ----
__global__ __launch_bounds__(256) void build_order(
    const int* __restrict__ coords, unsigned int* __restrict__ order)
{
    __shared__ unsigned short cnt[256][18];   // padded: odd word-stride, no conflicts
    __shared__ unsigned short part[16][17];
    __shared__ unsigned int   base[16];

    const int t = threadIdx.x;
    const int b = blockIdx.x;
    const int key16 = t >> 4;
    const int sub   = t & 15;

    #pragma unroll
    for (int k = 0; k < 16; ++k) cnt[t][k] = 0;
    __syncthreads();

    const int2* c2 = (const int2*)coords;
    unsigned int pk[16];
    #pragma unroll
    for (int i = 0; i < 16; ++i) {
        const int p = (b << 12) + (i << 8) + t;
        const int2 hw = c2[p];
        pk[i] = ((unsigned)b << 18) | ((unsigned)hw.x << 9) | (unsigned)hw.y;
        cnt[t][hw.x >> 5]++;
    }
    __syncthreads();

    unsigned run = 0;
    #pragma unroll
    for (int tt = sub * 16; tt < sub * 16 + 16; ++tt) run += cnt[tt][key16];
    part[key16][sub] = (unsigned short)run;
    __syncthreads();

    if (t < 16) {
        unsigned r = 0;
        #pragma unroll
        for (int s = 0; s < 16; ++s) { unsigned v = part[t][s]; part[t][s] = (unsigned short)r; r += v; }
        base[t] = r;
    }
    __syncthreads();
    if (t == 0) {
        unsigned r = 0;
        #pragma unroll
        for (int k = 0; k < 16; ++k) { unsigned v = base[k]; base[k] = r; r += v; }
    }
    __syncthreads();

    {
        unsigned r = part[key16][sub];
        #pragma unroll
        for (int tt = sub * 16; tt < sub * 16 + 16; ++tt) {
            unsigned v = cnt[tt][key16]; cnt[tt][key16] = (unsigned short)r; r += v;
        }
    }
    __syncthreads();

    #pragma unroll
    for (int i = 0; i < 16; ++i) {
        const unsigned key = (pk[i] >> 14) & 15;
        const unsigned pos = base[key] + cnt[t][key];
        cnt[t][key]++;
        order[(b << 12) + pos] = pk[i];
    }
}

// ---- kernel 2: row-per-lane, 4 patches/wave, fused final reduction ----
__global__ __launch_bounds__(256) void patch_stage1(
    const float* __restrict__ fuse,
    const float* __restrict__ img1,
    const float* __restrict__ img2,
    const unsigned int* __restrict__ order,
    float* __restrict__ partials,
    unsigned int* __restrict__ donecnt,
    float* __restrict__ out)
{
    const int lane = threadIdx.x & 63;
    const int wave = threadIdx.x >> 6;
    const int bid  = blockIdx.x;
    // bijective XCD-contiguous swizzle over sorted slots (NBLK % 8 == 0)
    const int slotblk = (bid & 7) * (NBLK / 8) + (bid >> 3);
    const int slot    = slotblk * PPB + wave * PPW + (lane >> 4);

    const unsigned v = order[slot];     // uniform within each 16-lane group
    const int w = v & 511;
    const int h = (v >> 9) & 511;
    const int b = v >> 18;
    const int r = lane & 15;            // this lane's patch row

    const size_t pb = (size_t)(b * CD) * PLANE + (size_t)(h + r) * WD + w;

    float acc = 0.f;
    const float inv = 1.f / 256.f;

    #pragma unroll
    for (int c = 0; c < CD; ++c) {
        const float* pf = fuse + pb + (size_t)c * PLANE;
        const float* p1 = img1 + pb + (size_t)c * PLANE;
        const float* p2 = img2 + pb + (size_t)c * PLANE;

        // 12 f4 loads: this lane's full 16-float row from each image
        const f4 vf0 = *(const f4*)(pf);      const f4 vf1 = *(const f4*)(pf + 4);
        const f4 vf2 = *(const f4*)(pf + 8);  const f4 vf3 = *(const f4*)(pf + 12);
        const f4 a0  = *(const f4*)(p1);      const f4 a1  = *(const f4*)(p1 + 4);
        const f4 a2  = *(const f4*)(p1 + 8);  const f4 a3  = *(const f4*)(p1 + 12);
        const f4 b0  = *(const f4*)(p2);      const f4 b1  = *(const f4*)(p2 + 4);
        const f4 b2  = *(const f4*)(p2 + 8);  const f4 b3  = *(const f4*)(p2 + 12);

        // in-lane stats over the 16-float row (VALU, no shuffles)
        const f4 sa = (a0 + a1) + (a2 + a3);
        float s1 = sa.x + sa.y + sa.z + sa.w;
        f4 qa = a0 * a0; qa += a1 * a1; qa += a2 * a2; qa += a3 * a3;
        float q1 = qa.x + qa.y + qa.z + qa.w;
        const f4 sb = (b0 + b1) + (b2 + b3);
        float s2 = sb.x + sb.y + sb.z + sb.w;
        f4 qb = b0 * b0; qb += b1 * b1; qb += b2 * b2; qb += b3 * b3;
        float q2 = qb.x + qb.y + qb.z + qb.w;

        // 16-lane butterfly (stays within this patch's lane group)
        #pragma unroll
        for (int off = 8; off >= 1; off >>= 1) {
            s1 += __shfl_xor(s1, off, 64);
            q1 += __shfl_xor(q1, off, 64);
            s2 += __shfl_xor(s2, off, 64);
            q2 += __shfl_xor(q2, off, 64);
        }

        const float mu1 = s1 * inv;
        const float mu2 = s2 * inv;
        const float sd1 = sqrtf(fmaxf(q1 * inv - mu1 * mu1, 0.f));
        const float sd2 = sqrtf(fmaxf(q2 * inv - mu2 * mu2, 0.f));
        const float den = sd1 + sd2 + 1e-6f;
        const float w1 = sd1 / den;
        const float w2 = sd2 / den;

        const f4 d0 = vf0 - (w1 * a0 + w2 * b0);
        const f4 d1 = vf1 - (w1 * a1 + w2 * b1);
        const f4 d2 = vf2 - (w1 * a2 + w2 * b2);
        const f4 d3 = vf3 - (w1 * a3 + w2 * b3);
        acc += (fabsf(d0.x) + fabsf(d0.y)) + (fabsf(d0.z) + fabsf(d0.w))
             + (fabsf(d1.x) + fabsf(d1.y)) + (fabsf(d1.z) + fabsf(d1.w))
             + (fabsf(d2.x) + fabsf(d2.y)) + (fabsf(d2.z) + fabsf(d2.w))
             + (fabsf(d3.x) + fabsf(d3.y)) + (fabsf(d3.z) + fabsf(d3.w));
    }

    // full-wave butterfly on acc (all 4 patches summed together)
    #pragma unroll
    for (int off = 32; off >= 1; off >>= 1)
        acc += __shfl_xor(acc, off, 64);

    __shared__ float partsm[4];
    __shared__ unsigned isLast;
    if (lane == 0) partsm[wave] = acc;
    __syncthreads();
    if (threadIdx.x == 0) {
        partials[bid] = partsm[0] + partsm[1] + partsm[2] + partsm[3];
        __threadfence();                       // make partial visible device-wide
        isLast = (atomicAdd(donecnt, 1u) == NBLK - 1) ? 1u : 0u;
    }
    __syncthreads();

    if (isLast) {
        __threadfence();                       // acquire: see all partials
        float s = 0.f;
        for (int i = threadIdx.x; i < NBLK; i += 256)
            s += partials[i];
        #pragma unroll
        for (int off = 32; off >= 1; off >>= 1)
            s += __shfl_xor(s, off, 64);
        __syncthreads();                       // partsm reuse
        if (lane == 0) partsm[wave] = s;
        __syncthreads();
        if (threadIdx.x == 0)
            out[0] = (partsm[0] + partsm[1] + partsm[2] + partsm[3])
                     * (float)(1.0 / TOTAL_ELEMS);
    }
}

extern "C" void kernel_launch(void* const* d_in, const int* in_sizes, int n_in,
                              void* d_out, int out_size, void* d_ws, size_t ws_size,
                              hipStream_t stream) {
    const float* fuse   = (const float*)d_in[0];
    const float* img1   = (const float*)d_in[1];
    const float* img2   = (const float*)d_in[2];
    const int*   coords = (const int*)d_in[3];
    float* out = (float*)d_out;

    unsigned int* order    = (unsigned int*)d_ws;                   // 64 KB
    float*        partials = (float*)((char*)d_ws + NP * 4);        // 4 KB
    unsigned int* donecnt  = (unsigned int*)((char*)d_ws + NP * 4 + NBLK * 4);

    hipMemsetAsync(donecnt, 0, sizeof(unsigned int), stream);
    build_order<<<BD, 256, 0, stream>>>(coords, order);
    patch_stage1<<<NBLK, 256, 0, stream>>>(fuse, img1, img2, order,
                                           partials, donecnt, out);
}